// Round 6
// baseline (462.517 us; speedup 1.0000x reference)
//
#include <hip/hip_runtime.h>

typedef unsigned short ushort_t;
typedef unsigned int u32;
typedef __attribute__((ext_vector_type(8))) short short8;
typedef __attribute__((ext_vector_type(4))) float floatx4;
typedef __attribute__((ext_vector_type(16))) float floatx16;
typedef __attribute__((ext_vector_type(2))) unsigned int uintx2;
typedef __attribute__((ext_vector_type(4))) unsigned int uintx4;

typedef const __attribute__((address_space(1))) u32* gptr_t;
typedef __attribute__((address_space(3))) u32* lptr_t;

__device__ __forceinline__ void async_copy16(void* lds, const void* g) {
  __builtin_amdgcn_global_load_lds((gptr_t)g, (lptr_t)lds, 16, 0, 0);
}

__device__ __forceinline__ ushort_t f2bf(float f) {  // RNE
  u32 u = __float_as_uint(f);
  u += 0x7fffu + ((u >> 16) & 1u);
  return (ushort_t)(u >> 16);
}

__device__ __forceinline__ floatx4 mfma16(short8 a, short8 b, floatx4 c) {
  return __builtin_amdgcn_mfma_f32_16x16x32_bf16(a, b, c, 0, 0, 0);
}

__device__ __forceinline__ floatx16 mfma32(short8 a, short8 b, floatx16 c) {
  return __builtin_amdgcn_mfma_f32_32x32x16_bf16(a, b, c, 0, 0, 0);
}

__device__ __forceinline__ u32 cvt_pk_bf16(float lo, float hi) {
  u32 r;
  asm("v_cvt_pk_bf16_f32 %0, %1, %2" : "=v"(r) : "v"(lo), "v"(hi));
  return r;
}

// Cross-half exchange: from per-lane C-layout pairs (a[2j],a[2j+1]) build the
// B-operand fragment (k = (lane>>5)*8 + j).
__device__ __forceinline__ short8 mkfrag(u32 x0, u32 x1, u32 x2, u32 x3) {
  uintx2 ra = __builtin_amdgcn_permlane32_swap(x0, x2, false, false);
  uintx2 rb = __builtin_amdgcn_permlane32_swap(x1, x3, false, false);
  union { uintx4 u; short8 s; } t;
  t.u[0] = ra[0]; t.u[1] = rb[0]; t.u[2] = ra[1]; t.u[3] = rb[1];
  return t.s;
}

struct alignas(16) F4 { float a, b, c, d; };
struct alignas(8) U4 { ushort_t a, b, c, d; };

#define QSCALE 0.18033688011112043f /* 0.125 * log2(e): softmax in exp2 domain */

// ---------------- fused prep: x fp32->bf16 + 4x LoRA merge ----------------
__global__ __launch_bounds__(256) void prep_kernel(
    const float* __restrict__ x, ushort_t* __restrict__ xs,
    const float* __restrict__ W0, const float* __restrict__ dW0, const float* __restrict__ dB0,
    const float* __restrict__ W1, const float* __restrict__ dW1, const float* __restrict__ dB1,
    const float* __restrict__ W2, const float* __restrict__ dW2, const float* __restrict__ dB2,
    const float* __restrict__ W3, const float* __restrict__ dW3, const float* __restrict__ dB3,
    ushort_t* __restrict__ Wm) {
  const int bid = blockIdx.x;
  if (bid < 4096) {
    int i = bid * 256 + threadIdx.x;
    F4 v = ((const F4*)x)[i];
    U4 hh = {f2bf(v.a), f2bf(v.b), f2bf(v.c), f2bf(v.d)};
    ((U4*)xs)[i] = hh;
    return;
  }
  const int t = bid - 4096;
  const int layer = t >> 7, sub = t & 127;
  const float* W = (layer == 0) ? W0 : (layer == 1) ? W1 : (layer == 2) ? W2 : W3;
  const float* dW = (layer == 0) ? dW0 : (layer == 1) ? dW1 : (layer == 2) ? dW2 : dW3;
  const float* dB = (layer == 0) ? dB0 : (layer == 1) ? dB1 : (layer == 2) ? dB2 : dB3;
  ushort_t* Wh = Wm + (size_t)layer * 1024 * 1024;
  const int ot = sub * 8;
  const int d0 = threadIdx.x * 4;
  float acc[8][4] = {};
  for (int r = 0; r < 32; ++r) {
    F4 w = *(const F4*)&dW[r * 1024 + d0];
    float wv[4] = {w.a, w.b, w.c, w.d};
#pragma unroll
    for (int o = 0; o < 8; ++o) {
      float s = dB[(ot + o) * 32 + r];
#pragma unroll
      for (int j = 0; j < 4; ++j) acc[o][j] += s * wv[j];
    }
  }
#pragma unroll
  for (int o = 0; o < 8; ++o) {
    F4 w = *(const F4*)&W[(ot + o) * 1024 + d0];
    U4 hh = {f2bf(w.a + acc[o][0]), f2bf(w.b + acc[o][1]),
             f2bf(w.c + acc[o][2]), f2bf(w.d + acc[o][3])};
    *(U4*)&Wh[(ot + o) * 1024 + d0] = hh;
  }
}

// ---------------- bf16 GEMM, double-buffered: C = A @ B^T + bias ----------------
// Tile 128(M) x TN(N). MODE 0 (TN=128): Q cols (<1024) scaled by QSCALE -> qk
// (stride 2048); K cols -> qk; V cols (>=2048) ONLY to vt transposed per (b,h),
// U4-packed over 4 consecutive n. MODE 1 (fp32 out): SWAPPED operands
// mfma16(b,a) so D's quad*4+r axis = output COLUMN -> bias+store as F4.
template <int MODE, int TN>
__global__ __launch_bounds__(256) void gemm_bt(
    const ushort_t* __restrict__ A, const ushort_t* __restrict__ B,
    const float* __restrict__ b0, const float* __restrict__ b1,
    const float* __restrict__ b2,
    ushort_t* __restrict__ C, ushort_t* __restrict__ vth,
    float* __restrict__ Cf, const int M, const int N, const int K) {
  constexpr int NT2 = TN / 32;  // acc col-tiles per wave
  __shared__ __align__(16) ushort_t lA[2][128 * 32], lB[2][TN * 32];
  const int tid = threadIdx.x;
  const int wave = tid >> 6, lane = tid & 63;
  const int lo4 = lane & 15, quad = lane >> 4;
  const int n0 = blockIdx.x * TN, m0 = blockIdx.y * 128;
  const int wm = (wave >> 1) * 64, wn = (wave & 1) * (TN / 2);

  floatx4 acc[4][NT2];
  const floatx4 zero4 = {0.f, 0.f, 0.f, 0.f};
#pragma unroll
  for (int mt = 0; mt < 4; ++mt)
#pragma unroll
    for (int nt = 0; nt < NT2; ++nt) acc[mt][nt] = zero4;

  const int strow = lane >> 2;       // 0..15
  const int stcol = (lane & 3) * 8;  // 0,8,16,24

  const int NTILES = K >> 5;
  {
#pragma unroll
    for (int i = 0; i < 2; ++i) {
      const int g = wave * 2 + i;
      async_copy16(&lA[0][g * 512], A + (size_t)(m0 + g * 16 + strow) * K + stcol);
    }
#pragma unroll
    for (int i = 0; i < TN / 64; ++i) {
      const int g = wave * (TN / 64) + i;
      async_copy16(&lB[0][g * 512], B + (size_t)(n0 + g * 16 + strow) * K + stcol);
    }
  }
  __syncthreads();

  for (int t = 0; t < NTILES; ++t) {
    const int cur = t & 1;
    if (t + 1 < NTILES) {
      const int kk = (t + 1) << 5;
#pragma unroll
      for (int i = 0; i < 2; ++i) {
        const int g = wave * 2 + i;
        async_copy16(&lA[cur ^ 1][g * 512], A + (size_t)(m0 + g * 16 + strow) * K + kk + stcol);
      }
#pragma unroll
      for (int i = 0; i < TN / 64; ++i) {
        const int g = wave * (TN / 64) + i;
        async_copy16(&lB[cur ^ 1][g * 512], B + (size_t)(n0 + g * 16 + strow) * K + kk + stcol);
      }
    }
    short8 a_[4], b_[NT2];
#pragma unroll
    for (int t2 = 0; t2 < 4; ++t2)
      a_[t2] = *(const short8*)&lA[cur][(wm + t2 * 16 + lo4) * 32 + quad * 8];
#pragma unroll
    for (int t2 = 0; t2 < NT2; ++t2)
      b_[t2] = *(const short8*)&lB[cur][(wn + t2 * 16 + lo4) * 32 + quad * 8];
#pragma unroll
    for (int mt = 0; mt < 4; ++mt)
#pragma unroll
      for (int nt = 0; nt < NT2; ++nt)
        acc[mt][nt] = (MODE == 0) ? mfma16(a_[mt], b_[nt], acc[mt][nt])
                                  : mfma16(b_[nt], a_[mt], acc[mt][nt]);
    if (t + 1 < NTILES) __syncthreads();
  }

  if (MODE == 0) {
#pragma unroll
    for (int nt = 0; nt < NT2; ++nt) {
      const int col = n0 + wn + nt * 16 + lo4;
      const float bias =
          (col < 1024) ? b0[col] : (col < 2048) ? b1[col - 1024] : b2[col - 2048];
      if (col < 2048) {  // Q|K: scalar stores (lanes 0-15 consecutive cols = 32B)
#pragma unroll
        for (int mt = 0; mt < 4; ++mt)
#pragma unroll
          for (int r = 0; r < 4; ++r) {
            const int row = m0 + wm + mt * 16 + quad * 4 + r;
            float c = acc[mt][nt][r] + bias;
            if (col < 1024) c *= QSCALE;  // pre-scale Q for exp2-domain softmax
            C[(size_t)row * 2048 + col] = f2bf(c);
          }
      } else {  // V: vt[(b*16+h)*64+d][n]; r -> 4 consecutive n => U4 pack
        const int d = col - 2048;
#pragma unroll
        for (int mt = 0; mt < 4; ++mt) {
          const int rowb = m0 + wm + mt * 16 + quad * 4;
          const size_t vrow = (size_t)(((rowb >> 11) * 16 + (d >> 6)) * 64 + (d & 63));
          U4 hh = {f2bf(acc[mt][nt][0] + bias), f2bf(acc[mt][nt][1] + bias),
                   f2bf(acc[mt][nt][2] + bias), f2bf(acc[mt][nt][3] + bias)};
          *(U4*)&vth[vrow * 2048 + (rowb & 2047)] = hh;
        }
      }
    }
  } else {  // MODE 1 (swapped): row = ...+lo4, col = ...+quad*4+r -> F4 store
#pragma unroll
    for (int nt = 0; nt < NT2; ++nt) {
      const int col0 = n0 + wn + nt * 16 + quad * 4;
      const F4 bv = *(const F4*)&b0[col0];
#pragma unroll
      for (int mt = 0; mt < 4; ++mt) {
        const int row = m0 + wm + mt * 16 + lo4;
        F4 o = {acc[mt][nt][0] + bv.a, acc[mt][nt][1] + bv.b,
                acc[mt][nt][2] + bv.c, acc[mt][nt][3] + bv.d};
        *(F4*)&Cf[(size_t)row * N + col0] = o;
      }
    }
  }
}

// ---------------- flash attention: 32x32 swapped-QK, K-split, deferred-P (T15) ----------------
// grid 512 blocks (XCD-grouped) x 512 thr (8 waves = 4 q-groups x 2 key-halves),
// 2 blocks/CU = 4 waves/SIMD. S^T = mfma(K, Q^T): softmax row lane-local.
// DEFERRED-P pipeline: iter t runs QK(t) then immediately PV(t-1) (carried
// packed P, 16 VGPR), so softmax VALU of tile t executes in the shadow of
// PV's MFMAs instead of between the two MFMA clusters. V is a 3-deep ring
// (PV(t-1) reads V[(t-1)%3] while STAGE writes V[(t+1)%3]); K stays 2-deep.
// LDS 80KB (2 blocks/CU exactly). One __syncthreads per iter (same proven
// drain semantics as before). Full unroll -> all ring indices static.
__global__ __launch_bounds__(512, 4) void attn_kernel(
    const ushort_t* __restrict__ qk, const ushort_t* __restrict__ vt,
    ushort_t* __restrict__ at) {
  __shared__ __align__(16) ushort_t Kh[2][2][64 * 64];  // [kbuf][half][key][d] 32KB
  __shared__ __align__(16) ushort_t Vh[3][2][64 * 64];  // [vbuf][half][d][key] 48KB
  const int bid = blockIdx.x;
  const int xcd = bid & 7, g = bid >> 3;
  const int bh = xcd * 4 + (g >> 4), qt = g & 15;  // bh-groups pinned per XCD
  const int b = bh >> 4, h = bh & 15;
  const int tid = threadIdx.x;
  const int wave = tid >> 6, lane = tid & 63;
  const int rowg = wave & 3, half = wave >> 2;
  const int l31 = lane & 31, hi = lane >> 5, l7 = lane & 7;
  const int hi8 = hi * 8;

  // Q B-frags (col=q=l31, k=d) — pre-scaled by QSCALE
  short8 qf[4];
  {
    const ushort_t* gq =
        qk + (size_t)(b * 2048 + qt * 128 + rowg * 32 + l31) * 2048 + h * 64 + hi8;
#pragma unroll
    for (int st = 0; st < 4; ++st) qf[st] = *(const short8*)(gq + st * 16);
  }

  floatx16 O[2], zero16;
#pragma unroll
  for (int i = 0; i < 16; ++i) { O[0][i] = 0.f; O[1][i] = 0.f; zero16[i] = 0.f; }
  float l_acc[4] = {0.f, 0.f, 0.f, 0.f};
  u32 pa0[8], pa1[8];  // carried packed P of tile t-1

  // staging role: stile = wave>>1 (0:K-h0 1:K-h1 2:V-h0 3:V-h1), spart = wave&1
  const int stile = wave >> 1, spart = wave & 1;
  const int strow = lane >> 3;         // 0..7
  const int stswz = (l7 ^ strow) * 8;  // pre-swizzled source chunk (elements)
  const ushort_t* Ksrc = qk + (size_t)b * 2048 * 2048 + 1024 + h * 64;  // [key][d]
  const ushort_t* Vsrc = vt + (size_t)bh * 64 * 2048;                   // [d][key]

#define STAGE(kb_, vb_, t_)                                                        \
  {                                                                                \
    const int kt_ = 2 * (t_) + (stile & 1);                                        \
    if (stile < 2) {                                                               \
      const ushort_t* s_ =                                                         \
          Ksrc + (size_t)(kt_ * 64 + spart * 32 + strow) * 2048 + stswz;           \
      ushort_t* d_ = &Kh[kb_][stile & 1][spart * 32 * 64];                         \
      _Pragma("unroll") for (int i_ = 0; i_ < 4; ++i_)                             \
          async_copy16(d_ + i_ * 512, s_ + (size_t)i_ * 8 * 2048);                 \
    } else {                                                                       \
      const ushort_t* s_ =                                                         \
          Vsrc + (size_t)(spart * 32 + strow) * 2048 + kt_ * 64 + stswz;           \
      ushort_t* d_ = &Vh[vb_][stile & 1][spart * 32 * 64];                         \
      _Pragma("unroll") for (int i_ = 0; i_ < 4; ++i_)                             \
          async_copy16(d_ + i_ * 512, s_ + (size_t)i_ * 8 * 2048);                 \
    }                                                                              \
  }

  // QK(t): S^T = K @ Q^T (fresh start from zero16, no acc zero-init movs)
#define QKBLK(kb_, s0_, s1_)                                                       \
  {                                                                                \
    const ushort_t* kb = &Kh[kb_][half][0];                                        \
    __builtin_amdgcn_s_setprio(1);                                                 \
    s0_ = mfma32(*(const short8*)&kb[l31 * 64 + ((0 + hi) ^ l7) * 8], qf[0], zero16); \
    s1_ = mfma32(*(const short8*)&kb[(32 + l31) * 64 + ((0 + hi) ^ l7) * 8], qf[0],   \
                 zero16);                                                          \
    _Pragma("unroll") for (int st = 1; st < 4; ++st) {                             \
      const int c = ((st * 2 + hi) ^ l7) * 8;                                      \
      s0_ = mfma32(*(const short8*)&kb[l31 * 64 + c], qf[st], s0_);                \
      s1_ = mfma32(*(const short8*)&kb[(32 + l31) * 64 + c], qf[st], s1_);         \
    }                                                                              \
    __builtin_amdgcn_s_setprio(0);                                                 \
  }

  // PV(t-1): O^T += V^T @ P^T from carried packed P
#define PVBLK(vb_)                                                                 \
  {                                                                                \
    short8 pb00 = mkfrag(pa0[0], pa0[1], pa0[2], pa0[3]);                          \
    short8 pb01 = mkfrag(pa0[4], pa0[5], pa0[6], pa0[7]);                          \
    short8 pb10 = mkfrag(pa1[0], pa1[1], pa1[2], pa1[3]);                          \
    short8 pb11 = mkfrag(pa1[4], pa1[5], pa1[6], pa1[7]);                          \
    const ushort_t* vb = &Vh[vb_][half][0];                                        \
    __builtin_amdgcn_s_setprio(1);                                                 \
    _Pragma("unroll") for (int dblk = 0; dblk < 2; ++dblk) {                       \
      const int vr = (dblk * 32 + l31) * 64;                                       \
      O[dblk] = mfma32(*(const short8*)&vb[vr + ((0 + hi) ^ l7) * 8], pb00, O[dblk]); \
      O[dblk] = mfma32(*(const short8*)&vb[vr + ((2 + hi) ^ l7) * 8], pb01, O[dblk]); \
      O[dblk] = mfma32(*(const short8*)&vb[vr + ((4 + hi) ^ l7) * 8], pb10, O[dblk]); \
      O[dblk] = mfma32(*(const short8*)&vb[vr + ((6 + hi) ^ l7) * 8], pb11, O[dblk]); \
    }                                                                              \
    __builtin_amdgcn_s_setprio(0);                                                 \
  }

  // exp2 + row-sum + pack into the carried pa regs
#define PACK(s0_, s1_)                                                             \
  {                                                                                \
    _Pragma("unroll") for (int j = 0; j < 8; ++j) {                                \
      float p0a = __builtin_amdgcn_exp2f(s0_[2 * j]);                              \
      float p0b = __builtin_amdgcn_exp2f(s0_[2 * j + 1]);                          \
      float p1a = __builtin_amdgcn_exp2f(s1_[2 * j]);                              \
      float p1b = __builtin_amdgcn_exp2f(s1_[2 * j + 1]);                          \
      l_acc[j & 3] += (p0a + p0b) + (p1a + p1b);                                   \
      pa0[j] = cvt_pk_bf16(p0a, p0b);                                              \
      pa1[j] = cvt_pk_bf16(p1a, p1b);                                              \
    }                                                                              \
  }

  // ---- pipeline prologue: tile 0 staged, QK(0)+pack, tile 1 staged ----
  STAGE(0, 0, 0);
  __syncthreads();
  STAGE(1, 1, 1);
  {
    floatx16 s0, s1;
    QKBLK(0, s0, s1);
    PACK(s0, s1);
  }
  __syncthreads();

  // ---- main: iter t does QK(t), PV(t-1), pack(t) ----
#pragma unroll
  for (int t = 1; t < 16; ++t) {
    if (t < 15) STAGE((t + 1) & 1, (t + 1) % 3, t + 1);
    floatx16 s0, s1;
    QKBLK(t & 1, s0, s1);
    PVBLK((t - 1) % 3);
    PACK(s0, s1);
    if (t < 15) __syncthreads();
  }
  // ---- epilogue: PV(15) ----
  PVBLK(15 % 3);
#undef STAGE
#undef QKBLK
#undef PVBLK
#undef PACK

  // partial l for q=l31 over this wave's keys (this lane + partner hi-half)
  float l = (l_acc[0] + l_acc[1]) + (l_acc[2] + l_acc[3]);
  l += __shfl_xor(l, 32);

  // ---- K-split combine: waves 4-7 push partials via LDS, waves 0-3 merge ----
  float* Pf0 = (float*)&Kh[0][0][0];  // 4 regions x 64 lanes x 20 f32 = 20KB
  float* Pf1 = (float*)&Vh[0][0][0];
  __syncthreads();  // all tile reads done before LDS reuse
  if (half == 1) {
    const int base = rowg * 1280 + lane * 20;
#pragma unroll
    for (int j = 0; j < 16; ++j) Pf0[base + j] = O[0][j];
#pragma unroll
    for (int j = 0; j < 16; ++j) Pf1[base + j] = O[1][j];
    Pf0[base + 16] = l;
  }
  __syncthreads();
  if (half == 0) {
    const int base = rowg * 1280 + lane * 20;
#pragma unroll
    for (int j = 0; j < 16; ++j) O[0][j] += Pf0[base + j];
#pragma unroll
    for (int j = 0; j < 16; ++j) O[1][j] += Pf1[base + j];
    l += Pf0[base + 16];
    const float linv = 1.f / l;
    // O^T reg -> d = dblk*32 + 8*gr + 4*hi + r, q = l31
    ushort_t* out =
        at + (size_t)(b * 2048 + qt * 128 + rowg * 32 + l31) * 1024 + h * 64;
#pragma unroll
    for (int dblk = 0; dblk < 2; ++dblk)
#pragma unroll
      for (int gr = 0; gr < 4; ++gr) {
        U4 hh = {f2bf(O[dblk][4 * gr + 0] * linv), f2bf(O[dblk][4 * gr + 1] * linv),
                 f2bf(O[dblk][4 * gr + 2] * linv), f2bf(O[dblk][4 * gr + 3] * linv)};
        *(U4*)&out[dblk * 32 + gr * 8 + hi * 4] = hh;
      }
  }
}

extern "C" void kernel_launch(void* const* d_in, const int* in_sizes, int n_in,
                              void* d_out, int out_size, void* d_ws, size_t ws_size,
                              hipStream_t stream) {
  const float* x = (const float*)d_in[0];
  const float* qW = (const float*)d_in[1];
  const float* qb = (const float*)d_in[2];
  const float* qdW = (const float*)d_in[3];
  const float* qdB = (const float*)d_in[4];
  const float* kW = (const float*)d_in[5];
  const float* kb = (const float*)d_in[6];
  const float* kdW = (const float*)d_in[7];
  const float* kdB = (const float*)d_in[8];
  const float* vW = (const float*)d_in[9];
  const float* vb = (const float*)d_in[10];
  const float* vdW = (const float*)d_in[11];
  const float* vdB = (const float*)d_in[12];
  const float* oW = (const float*)d_in[13];
  const float* ob = (const float*)d_in[14];
  const float* odW = (const float*)d_in[15];
  const float* odB = (const float*)d_in[16];

  char* ws = (char*)d_ws;
  const size_t MB = 1024u * 1024u;
  const size_t WELEM = 1024u * 1024u;
  ushort_t* xs = (ushort_t*)(ws + 0 * MB);   // 8MB  (4096x1024)
  ushort_t* Wm = (ushort_t*)(ws + 8 * MB);   // 8MB  (4x1024x1024)
  ushort_t* qk = (ushort_t*)(ws + 16 * MB);  // 16MB (4096x2048: Q|K, Q pre-scaled)
  ushort_t* vt = (ushort_t*)(ws + 32 * MB);  // 8MB  (2048x2048 V^T per (b,h))
  ushort_t* at = xs;                         // reuse dead x for attention out

  prep_kernel<<<4608, 256, 0, stream>>>(x, xs, qW, qdW, qdB, kW, kdW, kdB,
                                        vW, vdW, vdB, oW, odW, odB, Wm);
  gemm_bt<0, 128><<<dim3(24, 32), 256, 0, stream>>>(xs, Wm, qb, kb, vb,
                                                    qk, vt, nullptr, 4096, 3072, 1024);
  attn_kernel<<<512, 512, 0, stream>>>(qk, vt, at);
  gemm_bt<1, 64><<<dim3(16, 32), 256, 0, stream>>>(at, Wm + 3 * WELEM, ob, nullptr,
                                                   nullptr, nullptr, nullptr,
                                                   (float*)d_out, 4096, 1024, 1024);
}

// Round 7
// 216.715 us; speedup vs baseline: 2.1342x; 2.1342x over previous
//
#include <hip/hip_runtime.h>

typedef unsigned short ushort_t;
typedef unsigned int u32;
typedef __attribute__((ext_vector_type(8))) short short8;
typedef __attribute__((ext_vector_type(4))) float floatx4;
typedef __attribute__((ext_vector_type(16))) float floatx16;
typedef __attribute__((ext_vector_type(2))) unsigned int uintx2;
typedef __attribute__((ext_vector_type(4))) unsigned int uintx4;

typedef const __attribute__((address_space(1))) u32* gptr_t;
typedef __attribute__((address_space(3))) u32* lptr_t;

__device__ __forceinline__ void async_copy16(void* lds, const void* g) {
  __builtin_amdgcn_global_load_lds((gptr_t)g, (lptr_t)lds, 16, 0, 0);
}

__device__ __forceinline__ ushort_t f2bf(float f) {  // RNE
  u32 u = __float_as_uint(f);
  u += 0x7fffu + ((u >> 16) & 1u);
  return (ushort_t)(u >> 16);
}

__device__ __forceinline__ floatx4 mfma16(short8 a, short8 b, floatx4 c) {
  return __builtin_amdgcn_mfma_f32_16x16x32_bf16(a, b, c, 0, 0, 0);
}

__device__ __forceinline__ floatx16 mfma32(short8 a, short8 b, floatx16 c) {
  return __builtin_amdgcn_mfma_f32_32x32x16_bf16(a, b, c, 0, 0, 0);
}

__device__ __forceinline__ u32 cvt_pk_bf16(float lo, float hi) {
  u32 r;
  asm("v_cvt_pk_bf16_f32 %0, %1, %2" : "=v"(r) : "v"(lo), "v"(hi));
  return r;
}

// Cross-half exchange: from per-lane C-layout pairs (a[2j],a[2j+1]) build the
// B-operand fragment (k = (lane>>5)*8 + j).
__device__ __forceinline__ short8 mkfrag(u32 x0, u32 x1, u32 x2, u32 x3) {
  uintx2 ra = __builtin_amdgcn_permlane32_swap(x0, x2, false, false);
  uintx2 rb = __builtin_amdgcn_permlane32_swap(x1, x3, false, false);
  union { uintx4 u; short8 s; } t;
  t.u[0] = ra[0]; t.u[1] = rb[0]; t.u[2] = ra[1]; t.u[3] = rb[1];
  return t.s;
}

struct alignas(16) F4 { float a, b, c, d; };
struct alignas(8) U4 { ushort_t a, b, c, d; };

#define QSCALE 0.18033688011112043f /* 0.125 * log2(e): softmax in exp2 domain */

// ---------------- fused prep: x fp32->bf16 + 4x LoRA merge ----------------
__global__ __launch_bounds__(256) void prep_kernel(
    const float* __restrict__ x, ushort_t* __restrict__ xs,
    const float* __restrict__ W0, const float* __restrict__ dW0, const float* __restrict__ dB0,
    const float* __restrict__ W1, const float* __restrict__ dW1, const float* __restrict__ dB1,
    const float* __restrict__ W2, const float* __restrict__ dW2, const float* __restrict__ dB2,
    const float* __restrict__ W3, const float* __restrict__ dW3, const float* __restrict__ dB3,
    ushort_t* __restrict__ Wm) {
  const int bid = blockIdx.x;
  if (bid < 4096) {
    int i = bid * 256 + threadIdx.x;
    F4 v = ((const F4*)x)[i];
    U4 hh = {f2bf(v.a), f2bf(v.b), f2bf(v.c), f2bf(v.d)};
    ((U4*)xs)[i] = hh;
    return;
  }
  const int t = bid - 4096;
  const int layer = t >> 7, sub = t & 127;
  const float* W = (layer == 0) ? W0 : (layer == 1) ? W1 : (layer == 2) ? W2 : W3;
  const float* dW = (layer == 0) ? dW0 : (layer == 1) ? dW1 : (layer == 2) ? dW2 : dW3;
  const float* dB = (layer == 0) ? dB0 : (layer == 1) ? dB1 : (layer == 2) ? dB2 : dB3;
  ushort_t* Wh = Wm + (size_t)layer * 1024 * 1024;
  const int ot = sub * 8;
  const int d0 = threadIdx.x * 4;
  float acc[8][4] = {};
  for (int r = 0; r < 32; ++r) {
    F4 w = *(const F4*)&dW[r * 1024 + d0];
    float wv[4] = {w.a, w.b, w.c, w.d};
#pragma unroll
    for (int o = 0; o < 8; ++o) {
      float s = dB[(ot + o) * 32 + r];
#pragma unroll
      for (int j = 0; j < 4; ++j) acc[o][j] += s * wv[j];
    }
  }
#pragma unroll
  for (int o = 0; o < 8; ++o) {
    F4 w = *(const F4*)&W[(ot + o) * 1024 + d0];
    U4 hh = {f2bf(w.a + acc[o][0]), f2bf(w.b + acc[o][1]),
             f2bf(w.c + acc[o][2]), f2bf(w.d + acc[o][3])};
    *(U4*)&Wh[(ot + o) * 1024 + d0] = hh;
  }
}

// ---------------- bf16 GEMM, double-buffered: C = A @ B^T + bias ----------------
// Tile 128(M) x TN(N). MODE 0 (TN=128): Q cols (<1024) scaled by QSCALE -> qk
// (stride 2048); K cols -> qk; V cols (>=2048) ONLY to vt transposed per (b,h),
// U4-packed over 4 consecutive n. MODE 1 (fp32 out): SWAPPED operands
// mfma16(b,a) so D's quad*4+r axis = output COLUMN -> bias+store as F4.
// XCD-chunked block swizzle (T1, bijective: nwg%8==0): each XCD owns a
// contiguous chunk of m-rows so the A-panel working set stays L2-resident.
template <int MODE, int TN>
__global__ __launch_bounds__(256) void gemm_bt(
    const ushort_t* __restrict__ A, const ushort_t* __restrict__ B,
    const float* __restrict__ b0, const float* __restrict__ b1,
    const float* __restrict__ b2,
    ushort_t* __restrict__ C, ushort_t* __restrict__ vth,
    float* __restrict__ Cf, const int M, const int N, const int K) {
  constexpr int NT2 = TN / 32;  // acc col-tiles per wave
  __shared__ __align__(16) ushort_t lA[2][128 * 32], lB[2][TN * 32];
  const int tid = threadIdx.x;
  const int wave = tid >> 6, lane = tid & 63;
  const int lo4 = lane & 15, quad = lane >> 4;
  // XCD-chunked bijective swizzle of the linear block id (nwg % 8 == 0)
  int lid = blockIdx.y * gridDim.x + blockIdx.x;
  const int nwg = gridDim.x * gridDim.y;
  lid = (lid & 7) * (nwg >> 3) + (lid >> 3);
  const int n0 = (lid % gridDim.x) * TN, m0 = (lid / gridDim.x) * 128;
  const int wm = (wave >> 1) * 64, wn = (wave & 1) * (TN / 2);

  floatx4 acc[4][NT2];
  const floatx4 zero4 = {0.f, 0.f, 0.f, 0.f};
#pragma unroll
  for (int mt = 0; mt < 4; ++mt)
#pragma unroll
    for (int nt = 0; nt < NT2; ++nt) acc[mt][nt] = zero4;

  const int strow = lane >> 2;       // 0..15
  const int stcol = (lane & 3) * 8;  // 0,8,16,24

  const int NTILES = K >> 5;
  {
#pragma unroll
    for (int i = 0; i < 2; ++i) {
      const int g = wave * 2 + i;
      async_copy16(&lA[0][g * 512], A + (size_t)(m0 + g * 16 + strow) * K + stcol);
    }
#pragma unroll
    for (int i = 0; i < TN / 64; ++i) {
      const int g = wave * (TN / 64) + i;
      async_copy16(&lB[0][g * 512], B + (size_t)(n0 + g * 16 + strow) * K + stcol);
    }
  }
  __syncthreads();

  for (int t = 0; t < NTILES; ++t) {
    const int cur = t & 1;
    if (t + 1 < NTILES) {
      const int kk = (t + 1) << 5;
#pragma unroll
      for (int i = 0; i < 2; ++i) {
        const int g = wave * 2 + i;
        async_copy16(&lA[cur ^ 1][g * 512], A + (size_t)(m0 + g * 16 + strow) * K + kk + stcol);
      }
#pragma unroll
      for (int i = 0; i < TN / 64; ++i) {
        const int g = wave * (TN / 64) + i;
        async_copy16(&lB[cur ^ 1][g * 512], B + (size_t)(n0 + g * 16 + strow) * K + kk + stcol);
      }
    }
    short8 a_[4], b_[NT2];
#pragma unroll
    for (int t2 = 0; t2 < 4; ++t2)
      a_[t2] = *(const short8*)&lA[cur][(wm + t2 * 16 + lo4) * 32 + quad * 8];
#pragma unroll
    for (int t2 = 0; t2 < NT2; ++t2)
      b_[t2] = *(const short8*)&lB[cur][(wn + t2 * 16 + lo4) * 32 + quad * 8];
#pragma unroll
    for (int mt = 0; mt < 4; ++mt)
#pragma unroll
      for (int nt = 0; nt < NT2; ++nt)
        acc[mt][nt] = (MODE == 0) ? mfma16(a_[mt], b_[nt], acc[mt][nt])
                                  : mfma16(b_[nt], a_[mt], acc[mt][nt]);
    if (t + 1 < NTILES) __syncthreads();
  }

  if (MODE == 0) {
#pragma unroll
    for (int nt = 0; nt < NT2; ++nt) {
      const int col = n0 + wn + nt * 16 + lo4;
      const float bias =
          (col < 1024) ? b0[col] : (col < 2048) ? b1[col - 1024] : b2[col - 2048];
      if (col < 2048) {  // Q|K: scalar stores (lanes 0-15 consecutive cols = 32B)
#pragma unroll
        for (int mt = 0; mt < 4; ++mt)
#pragma unroll
          for (int r = 0; r < 4; ++r) {
            const int row = m0 + wm + mt * 16 + quad * 4 + r;
            float c = acc[mt][nt][r] + bias;
            if (col < 1024) c *= QSCALE;  // pre-scale Q for exp2-domain softmax
            C[(size_t)row * 2048 + col] = f2bf(c);
          }
      } else {  // V: vt[(b*16+h)*64+d][n]; r -> 4 consecutive n => U4 pack
        const int d = col - 2048;
#pragma unroll
        for (int mt = 0; mt < 4; ++mt) {
          const int rowb = m0 + wm + mt * 16 + quad * 4;
          const size_t vrow = (size_t)(((rowb >> 11) * 16 + (d >> 6)) * 64 + (d & 63));
          U4 hh = {f2bf(acc[mt][nt][0] + bias), f2bf(acc[mt][nt][1] + bias),
                   f2bf(acc[mt][nt][2] + bias), f2bf(acc[mt][nt][3] + bias)};
          *(U4*)&vth[vrow * 2048 + (rowb & 2047)] = hh;
        }
      }
    }
  } else {  // MODE 1 (swapped): row = ...+lo4, col = ...+quad*4+r -> F4 store
#pragma unroll
    for (int nt = 0; nt < NT2; ++nt) {
      const int col0 = n0 + wn + nt * 16 + quad * 4;
      const F4 bv = *(const F4*)&b0[col0];
#pragma unroll
      for (int mt = 0; mt < 4; ++mt) {
        const int row = m0 + wm + mt * 16 + lo4;
        F4 o = {acc[mt][nt][0] + bv.a, acc[mt][nt][1] + bv.b,
                acc[mt][nt][2] + bv.c, acc[mt][nt][3] + bv.d};
        *(F4*)&Cf[(size_t)row * N + col0] = o;
      }
    }
  }
}

// ---------------- flash attention: 32x32 swapped-QK, in-block K-split ----------------
// grid 512 blocks (XCD-grouped decode) x 512 thr (8 waves) = 2 blocks/CU,
// 16 waves/CU = 4 waves/SIMD. Waves {w, w+4} own the same 32 q-rows (rowg=w&3);
// half=w>>2 picks even/odd 64-key tiles. S^T = mfma(K, Q^T): softmax row
// lane-local; P packed in-register (cvt_pk + permlane32_swap). O^T = V^T @ P^T.
// Row-sum l via ones-A mfma32 on the packed P (exact sum of bf16 P used in PV;
// moves 32 adds/iter off the dominant VALU pipe). End: waves 4-7 push O,l
// partials through LDS; waves 0-3 merge, normalize, store.
__global__ __launch_bounds__(512, 4) void attn_kernel(
    const ushort_t* __restrict__ qk, const ushort_t* __restrict__ vt,
    ushort_t* __restrict__ at) {
  __shared__ __align__(16) ushort_t Kh[2][2][64 * 64];  // [dbuf][half][key][d] 32KB
  __shared__ __align__(16) ushort_t Vh[2][2][64 * 64];  // [dbuf][half][d][key] 32KB
  const int bid = blockIdx.x;
  const int xcd = bid & 7, g = bid >> 3;
  const int bh = xcd * 4 + (g >> 4), qt = g & 15;  // bh-groups pinned per XCD
  const int b = bh >> 4, h = bh & 15;
  const int tid = threadIdx.x;
  const int wave = tid >> 6, lane = tid & 63;
  const int rowg = wave & 3, half = wave >> 2;
  const int l31 = lane & 31, hi = lane >> 5, l7 = lane & 7;
  const int hi8 = hi * 8;

  // Q B-frags (col=q=l31, k=d) — pre-scaled by QSCALE
  short8 qf[4];
  {
    const ushort_t* gq =
        qk + (size_t)(b * 2048 + qt * 128 + rowg * 32 + l31) * 2048 + h * 64 + hi8;
#pragma unroll
    for (int st = 0; st < 4; ++st) qf[st] = *(const short8*)(gq + st * 16);
  }

  floatx16 O[2], Lacc;
#pragma unroll
  for (int i = 0; i < 16; ++i) { O[0][i] = 0.f; O[1][i] = 0.f; Lacc[i] = 0.f; }

  short8 onesf;  // bf16 1.0 broadcast (A-operand for the row-sum mfma)
  {
    union { uintx4 u; short8 s; } ou;
    ou.u[0] = 0x3F803F80u; ou.u[1] = 0x3F803F80u;
    ou.u[2] = 0x3F803F80u; ou.u[3] = 0x3F803F80u;
    onesf = ou.s;
  }

  // staging role: stile = wave>>1 (0:K-even 1:K-odd 2:V-even 3:V-odd), spart = wave&1
  const int stile = wave >> 1, spart = wave & 1;
  const int strow = lane >> 3;         // 0..7
  const int stswz = (l7 ^ strow) * 8;  // pre-swizzled source chunk (elements)
  const ushort_t* Ksrc = qk + (size_t)b * 2048 * 2048 + 1024 + h * 64;  // [key][d]
  const ushort_t* Vsrc = vt + (size_t)bh * 64 * 2048;                   // [d][key]

#define STAGE(buf, t_)                                                             \
  {                                                                                \
    const int kt_ = 2 * (t_) + (stile & 1);                                        \
    if (stile < 2) {                                                               \
      const ushort_t* s_ =                                                         \
          Ksrc + (size_t)(kt_ * 64 + spart * 32 + strow) * 2048 + stswz;           \
      ushort_t* d_ = &Kh[buf][stile & 1][spart * 32 * 64];                         \
      _Pragma("unroll") for (int i_ = 0; i_ < 4; ++i_)                             \
          async_copy16(d_ + i_ * 512, s_ + (size_t)i_ * 8 * 2048);                 \
    } else {                                                                       \
      const ushort_t* s_ =                                                         \
          Vsrc + (size_t)(spart * 32 + strow) * 2048 + kt_ * 64 + stswz;           \
      ushort_t* d_ = &Vh[buf][stile & 1][spart * 32 * 64];                         \
      _Pragma("unroll") for (int i_ = 0; i_ < 4; ++i_)                             \
          async_copy16(d_ + i_ * 512, s_ + (size_t)i_ * 8 * 2048);                 \
    }                                                                              \
  }

  STAGE(0, 0);
  __syncthreads();

  for (int t = 0; t < 16; ++t) {
    const int cur = t & 1;
    if (t + 1 < 16) STAGE(cur ^ 1, t + 1);

    // ---- S^T = K @ Q^T, two independent 32-key sub-tiles (exp2 domain) ----
    floatx16 s0, s1;
#pragma unroll
    for (int i = 0; i < 16; ++i) { s0[i] = 0.f; s1[i] = 0.f; }
    __builtin_amdgcn_s_setprio(1);
#pragma unroll
    for (int st = 0; st < 4; ++st) {
      const int c = ((st * 2 + hi) ^ l7) * 8;
      s0 = mfma32(*(const short8*)&Kh[cur][half][l31 * 64 + c], qf[st], s0);
      s1 = mfma32(*(const short8*)&Kh[cur][half][(32 + l31) * 64 + c], qf[st], s1);
    }
    __builtin_amdgcn_s_setprio(0);

    // ---- p = exp2(s); pack pairs to bf16 (row-sum done on MFMA pipe below) ----
    u32 a0[8], a1[8];
#pragma unroll
    for (int j = 0; j < 8; ++j) {
      a0[j] = cvt_pk_bf16(__builtin_amdgcn_exp2f(s0[2 * j]),
                          __builtin_amdgcn_exp2f(s0[2 * j + 1]));
      a1[j] = cvt_pk_bf16(__builtin_amdgcn_exp2f(s1[2 * j]),
                          __builtin_amdgcn_exp2f(s1[2 * j + 1]));
    }

    // ---- in-register cross-half exchange -> PV B-frags (P^T[key][q]) ----
    short8 pb00 = mkfrag(a0[0], a0[1], a0[2], a0[3]);  // keys  0..15
    short8 pb01 = mkfrag(a0[4], a0[5], a0[6], a0[7]);  // keys 16..31
    short8 pb10 = mkfrag(a1[0], a1[1], a1[2], a1[3]);  // keys 32..47
    short8 pb11 = mkfrag(a1[4], a1[5], a1[6], a1[7]);  // keys 48..63

    // ---- l += 1^T @ P^T ; O^T += V^T @ P^T ----
    __builtin_amdgcn_s_setprio(1);
    Lacc = mfma32(onesf, pb00, Lacc);
    Lacc = mfma32(onesf, pb01, Lacc);
    Lacc = mfma32(onesf, pb10, Lacc);
    Lacc = mfma32(onesf, pb11, Lacc);
#pragma unroll
    for (int dblk = 0; dblk < 2; ++dblk) {
      const int vr = (dblk * 32 + l31) * 64;
      O[dblk] = mfma32(*(const short8*)&Vh[cur][half][vr + ((0 + hi) ^ l7) * 8], pb00, O[dblk]);
      O[dblk] = mfma32(*(const short8*)&Vh[cur][half][vr + ((2 + hi) ^ l7) * 8], pb01, O[dblk]);
      O[dblk] = mfma32(*(const short8*)&Vh[cur][half][vr + ((4 + hi) ^ l7) * 8], pb10, O[dblk]);
      O[dblk] = mfma32(*(const short8*)&Vh[cur][half][vr + ((6 + hi) ^ l7) * 8], pb11, O[dblk]);
    }
    __builtin_amdgcn_s_setprio(0);
    if (t + 1 < 16) __syncthreads();
  }
#undef STAGE

  // partial l for q=l31 over this wave's keys: every Lacc reg holds the colsum
  // (ones-A makes all D rows equal; cols l31 and l31+32 identical -> no shfl)
  float l = Lacc[0];

  // ---- K-split combine: waves 4-7 push partials via LDS, waves 0-3 merge ----
  float* Pf0 = (float*)&Kh[0][0][0];  // 4 regions x 64 lanes x 20 f32 = 20KB
  float* Pf1 = (float*)&Vh[0][0][0];
  __syncthreads();  // all tile reads done before LDS reuse
  if (half == 1) {
    const int base = rowg * 1280 + lane * 20;
#pragma unroll
    for (int j = 0; j < 16; ++j) Pf0[base + j] = O[0][j];
#pragma unroll
    for (int j = 0; j < 16; ++j) Pf1[base + j] = O[1][j];
    Pf0[base + 16] = l;
  }
  __syncthreads();
  if (half == 0) {
    const int base = rowg * 1280 + lane * 20;
#pragma unroll
    for (int j = 0; j < 16; ++j) O[0][j] += Pf0[base + j];
#pragma unroll
    for (int j = 0; j < 16; ++j) O[1][j] += Pf1[base + j];
    l += Pf0[base + 16];
    const float linv = 1.f / l;
    // O^T reg -> d = dblk*32 + 8*gr + 4*hi + r, q = l31
    ushort_t* out =
        at + (size_t)(b * 2048 + qt * 128 + rowg * 32 + l31) * 1024 + h * 64;
#pragma unroll
    for (int dblk = 0; dblk < 2; ++dblk)
#pragma unroll
      for (int gr = 0; gr < 4; ++gr) {
        U4 hh = {f2bf(O[dblk][4 * gr + 0] * linv), f2bf(O[dblk][4 * gr + 1] * linv),
                 f2bf(O[dblk][4 * gr + 2] * linv), f2bf(O[dblk][4 * gr + 3] * linv)};
        *(U4*)&out[dblk * 32 + gr * 8 + hi * 4] = hh;
      }
  }
}

extern "C" void kernel_launch(void* const* d_in, const int* in_sizes, int n_in,
                              void* d_out, int out_size, void* d_ws, size_t ws_size,
                              hipStream_t stream) {
  const float* x = (const float*)d_in[0];
  const float* qW = (const float*)d_in[1];
  const float* qb = (const float*)d_in[2];
  const float* qdW = (const float*)d_in[3];
  const float* qdB = (const float*)d_in[4];
  const float* kW = (const float*)d_in[5];
  const float* kb = (const float*)d_in[6];
  const float* kdW = (const float*)d_in[7];
  const float* kdB = (const float*)d_in[8];
  const float* vW = (const float*)d_in[9];
  const float* vb = (const float*)d_in[10];
  const float* vdW = (const float*)d_in[11];
  const float* vdB = (const float*)d_in[12];
  const float* oW = (const float*)d_in[13];
  const float* ob = (const float*)d_in[14];
  const float* odW = (const float*)d_in[15];
  const float* odB = (const float*)d_in[16];

  char* ws = (char*)d_ws;
  const size_t MB = 1024u * 1024u;
  const size_t WELEM = 1024u * 1024u;
  ushort_t* xs = (ushort_t*)(ws + 0 * MB);   // 8MB  (4096x1024)
  ushort_t* Wm = (ushort_t*)(ws + 8 * MB);   // 8MB  (4x1024x1024)
  ushort_t* qk = (ushort_t*)(ws + 16 * MB);  // 16MB (4096x2048: Q|K, Q pre-scaled)
  ushort_t* vt = (ushort_t*)(ws + 32 * MB);  // 8MB  (2048x2048 V^T per (b,h))
  ushort_t* at = xs;                         // reuse dead x for attention out

  prep_kernel<<<4608, 256, 0, stream>>>(x, xs, qW, qdW, qdB, kW, kdW, kdB,
                                        vW, vdW, vdB, oW, odW, odB, Wm);
  gemm_bt<0, 128><<<dim3(24, 32), 256, 0, stream>>>(xs, Wm, qb, kb, vb,
                                                    qk, vt, nullptr, 4096, 3072, 1024);
  attn_kernel<<<512, 512, 0, stream>>>(qk, vt, at);
  gemm_bt<1, 64><<<dim3(16, 32), 256, 0, stream>>>(at, Wm + 3 * WELEM, ob, nullptr,
                                                   nullptr, nullptr, nullptr,
                                                   (float*)d_out, 4096, 1024, 1024);
}